// Round 10
// baseline (120.533 us; speedup 1.0000x reference)
//
#include <hip/hip_runtime.h>
#include <hip/hip_bf16.h>
#include <math.h>

#define BB 8
#define BS 65536  // 256*256

typedef __attribute__((ext_vector_type(8))) short short8v;
typedef __attribute__((ext_vector_type(4))) float f32x4;
typedef unsigned short u16;
typedef unsigned int u32;
typedef __attribute__((address_space(1))) const void gv_t;
typedef __attribute__((address_space(3))) void lv_t;

__device__ __forceinline__ u16 f2bf(float v) {
  __hip_bfloat16 h = __float2bfloat16(v);
  return *reinterpret_cast<u16*>(&h);
}

// MFMA LDS tiles: [32 rows][64 k] bf16 (4 KiB), row = 128 B = 8 chunks x 16 B.
// XOR swizzle cs = c ^ (r&7), applied identically on write and read (#21).
__device__ __forceinline__ short8v frag(const u16* lds, int rb, int sk,
                                        int lane) {
  int r = rb * 16 + (lane & 15);
  int c = sk * 4 + (lane >> 4);
  int cs = c ^ (r & 7);
  return *(const short8v*)(lds + r * 64 + cs * 8);
}

// gload_lds staging for a 32x64 bf16 tile: source pre-swizzled, LDS linear.
__device__ __forceinline__ void stage_g32(const u16* __restrict__ g, int row0,
                                          int stride, int k0, u16* lds,
                                          int tid) {
  int r = tid >> 3, c = tid & 7;
  int cs = c ^ (r & 7);
  const u16* src = g + (size_t)(row0 + r) * stride + k0 + cs * 8;
  u16* dst = lds + (size_t)(tid & ~63) * 8;  // wave-uniform base
  __builtin_amdgcn_global_load_lds((gv_t*)src, (lv_t*)dst, 16, 0, 0);
}

// ---------------------------------------------------------------------------
// D1: merged projection GEMMs, batch-affine (b = blockIdx & 7 -> XCD b).
//  L2p[b][n][dd] = |0.4a[dd]|*( sum_f x[f,n] W[dd,f] + b_lin[dd] )   (f32)
//  R2p[b][d2][n] = packed bf16 pair { R'(2*d2, n), R'(2*d2+1, n) }
//      where R'(dd,n) = |0.4a[dd]| * sum_f x[f,n] W[dd,256+f]
// Also zeroes the d23 barrier counters (block 0).
// 512 blocks x 256 thr; block = (b, n0 = (t>>3)*32, dd0 = (t&7)*32).
// ---------------------------------------------------------------------------
__global__ __launch_bounds__(256) void d1_proj(
    const float* __restrict__ x, const float* __restrict__ W,
    const float* __restrict__ b_lin, const float* __restrict__ a,
    float* __restrict__ L2p, u32* __restrict__ R2p, int* __restrict__ cnt) {
  __shared__ float xf[64][33];
  __shared__ u16 XT[32 * 64], B1[32 * 64], B2[32 * 64];
  const int bk = blockIdx.x, tid = threadIdx.x;
  const int b = bk & 7, t = bk >> 3;
  const int n0 = (t >> 3) * 32, dd0 = (t & 7) * 32;
  const int lane = tid & 63, wid = tid >> 6;
  const int nh = wid >> 1, dh = wid & 1;
  const float* xb = x + (size_t)b * BS;

  if (bk == 0 && tid < 8) cnt[tid] = 0;  // reset d23 barrier (pre-dispatch)

  const int r8 = tid >> 5, c32 = tid & 31;   // x-tile staging coords
  const int rw = tid >> 3, cw = tid & 7;     // W / XT staging coords

  f32x4 accL = f32x4{0.f, 0.f, 0.f, 0.f};
  f32x4 accR = f32x4{0.f, 0.f, 0.f, 0.f};

  for (int ks = 0; ks < 4; ++ks) {
    // P1: global loads -> regs, x -> LDS f32
    float xr[8];
#pragma unroll
    for (int it = 0; it < 8; ++it)
      xr[it] = xb[(size_t)(ks * 64 + it * 8 + r8) * 256 + n0 + c32];
    float4 wa0 = *(const float4*)&W[(size_t)(dd0 + rw) * 512 + ks * 64 + cw * 8];
    float4 wa1 = *(const float4*)&W[(size_t)(dd0 + rw) * 512 + ks * 64 + cw * 8 + 4];
    float4 wb0 = *(const float4*)&W[(size_t)(dd0 + rw) * 512 + 256 + ks * 64 + cw * 8];
    float4 wb1 = *(const float4*)&W[(size_t)(dd0 + rw) * 512 + 256 + ks * 64 + cw * 8 + 4];
#pragma unroll
    for (int it = 0; it < 8; ++it) xf[it * 8 + r8][c32] = xr[it];
    __syncthreads();
    // P2: XT (transposed x, bf16, swizzled) + B1/B2 (W rows, bf16, swizzled)
    {
      u16 o[8];
#pragma unroll
      for (int e = 0; e < 8; ++e) o[e] = f2bf(xf[cw * 8 + e][rw]);
      *(short8v*)&XT[rw * 64 + ((cw ^ (rw & 7)) * 8)] = *(const short8v*)o;
      u16 o1[8] = {f2bf(wa0.x), f2bf(wa0.y), f2bf(wa0.z), f2bf(wa0.w),
                   f2bf(wa1.x), f2bf(wa1.y), f2bf(wa1.z), f2bf(wa1.w)};
      *(short8v*)&B1[rw * 64 + ((cw ^ (rw & 7)) * 8)] = *(const short8v*)o1;
      u16 o2[8] = {f2bf(wb0.x), f2bf(wb0.y), f2bf(wb0.z), f2bf(wb0.w),
                   f2bf(wb1.x), f2bf(wb1.y), f2bf(wb1.z), f2bf(wb1.w)};
      *(short8v*)&B2[rw * 64 + ((cw ^ (rw & 7)) * 8)] = *(const short8v*)o2;
    }
    __syncthreads();
    // P3: MFMA
#pragma unroll
    for (int sk = 0; sk < 2; ++sk) {
      short8v xa = frag(XT, nh, sk, lane);
      short8v w1 = frag(B1, dh, sk, lane);
      short8v w2 = frag(B2, dh, sk, lane);
      accL = __builtin_amdgcn_mfma_f32_16x16x32_bf16(xa, w1, accL, 0, 0, 0);
      accR = __builtin_amdgcn_mfma_f32_16x16x32_bf16(w2, xa, accR, 0, 0, 0);
    }
  }

  // epilogue: L2p[n][dd] (f32)
  {
    int ddc = dd0 + dh * 16 + (lane & 15);
    float c2 = fabsf(0.4f * a[ddc]);
    float bl = b_lin[ddc];
    int nr = n0 + nh * 16 + ((lane >> 4) << 2);
#pragma unroll
    for (int q = 0; q < 4; ++q)
      L2p[(size_t)b * BS + (size_t)(nr + q) * 256 + ddc] = c2 * (accL[q] + bl);
  }
  // epilogue: R2p packed bf16 pairs [d2][n]
  {
    int nc = n0 + nh * 16 + (lane & 15);
    int ddr = dd0 + dh * 16 + ((lane >> 4) << 2);  // multiple of 4
    float r0 = fabsf(0.4f * a[ddr + 0]) * accR[0];
    float r1 = fabsf(0.4f * a[ddr + 1]) * accR[1];
    float r2 = fabsf(0.4f * a[ddr + 2]) * accR[2];
    float r3 = fabsf(0.4f * a[ddr + 3]) * accR[3];
    u32 p01 = (u32)f2bf(r0) | ((u32)f2bf(r1) << 16);
    u32 p23 = (u32)f2bf(r2) | ((u32)f2bf(r3) << 16);
    u32* Rp = R2p + (size_t)b * 32768;
    Rp[(size_t)(ddr >> 1) * 256 + nc] = p01;
    Rp[(size_t)((ddr >> 1) + 1) * 256 + nc] = p23;
  }
}

// ---------------------------------------------------------------------------
// D23: scores+softmax (phase A) | XCD-batch barrier | attn.v output (phase B).
// 512 blocks x 256 thr (2 blocks/CU guaranteed by cooperative launch).
// Phase A: block (b = bk&7, q = bk>>3): attn rows i0 = q*4 .. +3.
//   Per-thread work identical to R8's d2 (4 e-accumulators, 128 packed-R
//   iters, barrier-free). attnh rows -> global bf16 [i][j] (XCD-local L2).
// Barrier: per-batch counter, 64 blocks; release-fence / relaxed-spin /
//   acquire-fence. Correct regardless of XCD placement (device atomics).
// Phase B: R8's d3 body verbatim: block (b, f0=(t>>3)*32, i0f=(t&7)*32),
//   A = x rows reg-staged f32->bf16 (swizzled ds_write), B = attnh gload_lds.
// ---------------------------------------------------------------------------
__global__ __launch_bounds__(256, 2) void d23_fused(
    const u32* __restrict__ R2p, const float* __restrict__ L2p,
    const float* __restrict__ a, const int* __restrict__ adj,
    const float* __restrict__ bias, const float* __restrict__ x,
    u16* __restrict__ attnh, float* __restrict__ out, int* __restrict__ cnt) {
  __shared__ float4 Lq[256];     // L rows i0..i0+3 at col d
  __shared__ float2 sS2[128];    // sign pairs
  __shared__ float redm[4][4], reds[4][4];
  __shared__ u16 At[32 * 64], Bt[32 * 64];  // phase B
  const int tid = threadIdx.x, j = tid;
  const int bk = blockIdx.x, b = bk & 7, i0 = (bk >> 3) * 4;
  const int lane = tid & 63, wid = tid >> 6;
  const u32* Rb = R2p + (size_t)b * 32768;

  // ---------------- Phase A ----------------
  int adjv[4];
  float biasv[4];
#pragma unroll
  for (int ii = 0; ii < 4; ++ii) {
    int row = i0 + ii;
    adjv[ii] = adj[(size_t)b * BS + (size_t)row * 256 + j];
    biasv[ii] = bias[row * 256 + j];
  }
  {
    const float* Lb = L2p + (size_t)b * BS + (size_t)i0 * 256;
    Lq[j] = make_float4(Lb[j], Lb[256 + j], Lb[512 + j], Lb[768 + j]);
    if (tid < 128) {
      float2 av = *(const float2*)&a[2 * tid];
      sS2[tid] = make_float2(av.x >= 0.f ? 1.f : -1.f, av.y >= 0.f ? 1.f : -1.f);
    }
  }
  __syncthreads();

  float e0 = 0.f, e1 = 0.f, e2 = 0.f, e3 = 0.f, srj = 0.f;
#pragma unroll 8
  for (int d2 = 0; d2 < 128; ++d2) {
    u32 u = Rb[d2 * 256 + j];                       // coalesced dword, L2-hot
    float rv0 = __uint_as_float(u << 16);
    float rv1 = __uint_as_float(u & 0xffff0000u);
    float2 ss = sS2[d2];
    float4 lq0 = Lq[2 * d2];
    float4 lq1 = Lq[2 * d2 + 1];
    srj = fmaf(ss.x, rv0, srj);
    srj = fmaf(ss.y, rv1, srj);
    e0 = fmaf(ss.x, fabsf(lq0.x + rv0), e0);
    e1 = fmaf(ss.x, fabsf(lq0.y + rv0), e1);
    e2 = fmaf(ss.x, fabsf(lq0.z + rv0), e2);
    e3 = fmaf(ss.x, fabsf(lq0.w + rv0), e3);
    e0 = fmaf(ss.y, fabsf(lq1.x + rv1), e0);
    e1 = fmaf(ss.y, fabsf(lq1.y + rv1), e1);
    e2 = fmaf(ss.y, fabsf(lq1.z + rv1), e2);
    e3 = fmaf(ss.y, fabsf(lq1.w + rv1), e3);
  }

  float ev[4] = {e0, e1, e2, e3};
  const float sbase = 1.5f * srj;
  const float NEG_INF = -__builtin_inff();
#pragma unroll
  for (int ii = 0; ii < 4; ++ii) {
    ev[ii] += sbase + biasv[ii];
    ev[ii] = (adjv[ii] == 0) ? NEG_INF : ev[ii];
  }
#pragma unroll
  for (int ii = 0; ii < 4; ++ii) {
    float v = ev[ii];
#pragma unroll
    for (int off = 32; off >= 1; off >>= 1) v = fmaxf(v, __shfl_xor(v, off, 64));
    if (lane == 0) redm[wid][ii] = v;
  }
  __syncthreads();
  float p4[4];
#pragma unroll
  for (int ii = 0; ii < 4; ++ii) {
    float m = fmaxf(fmaxf(redm[0][ii], redm[1][ii]),
                    fmaxf(redm[2][ii], redm[3][ii]));
    p4[ii] = (m == NEG_INF) ? 1.f : __expf(ev[ii] - m);
  }
#pragma unroll
  for (int ii = 0; ii < 4; ++ii) {
    float v = p4[ii];
#pragma unroll
    for (int off = 32; off >= 1; off >>= 1) v += __shfl_xor(v, off, 64);
    if (lane == 0) reds[wid][ii] = v;
  }
  __syncthreads();
#pragma unroll
  for (int ii = 0; ii < 4; ++ii) {
    float ssum = reds[0][ii] + reds[1][ii] + reds[2][ii] + reds[3][ii];
    attnh[(size_t)b * BS + (size_t)(i0 + ii) * 256 + j] = f2bf(p4[ii] / ssum);
  }

  // ---------------- XCD-batch barrier (64 blocks of batch b) ----------------
  __threadfence();   // release: attnh stores visible device-wide
  __syncthreads();
  if (tid == 0) {
    __hip_atomic_fetch_add(&cnt[b], 1, __ATOMIC_RELEASE,
                           __HIP_MEMORY_SCOPE_AGENT);
    while (__hip_atomic_load(&cnt[b], __ATOMIC_RELAXED,
                             __HIP_MEMORY_SCOPE_AGENT) < 64)
      __builtin_amdgcn_s_sleep(8);
  }
  __syncthreads();
  __threadfence();   // acquire: no stale cached attnh

  // ---------------- Phase B (R8 d3 geometry, unchanged) ----------------
  {
    const int tt = bk >> 3;
    const int f0 = (tt >> 3) * 32, i0f = (tt & 7) * 32;
    const int fh = wid >> 1, ih2 = wid & 1;
    const float* Ax = x + (size_t)b * BS;
    const u16* Bb = attnh + (size_t)b * BS;
    const int rw = tid >> 3, cw = tid & 7;

    f32x4 acc = f32x4{0.f, 0.f, 0.f, 0.f};
    for (int ks = 0; ks < 4; ++ks) {
      stage_g32(Bb, i0f, 256, ks * 64, Bt, tid);
      {
        const float* src = Ax + (size_t)(f0 + rw) * 256 + ks * 64 + cw * 8;
        float4 v0 = *(const float4*)src;
        float4 v1 = *(const float4*)(src + 4);
        u16 o[8] = {f2bf(v0.x), f2bf(v0.y), f2bf(v0.z), f2bf(v0.w),
                    f2bf(v1.x), f2bf(v1.y), f2bf(v1.z), f2bf(v1.w)};
        *(short8v*)&At[rw * 64 + ((cw ^ (rw & 7)) * 8)] = *(const short8v*)o;
      }
      __syncthreads();
#pragma unroll
      for (int sk = 0; sk < 2; ++sk) {
        short8v af = frag(At, fh, sk, lane);
        short8v bf = frag(Bt, ih2, sk, lane);
        acc = __builtin_amdgcn_mfma_f32_16x16x32_bf16(af, bf, acc, 0, 0, 0);
      }
      __syncthreads();
    }

    int col = i0f + ih2 * 16 + (lane & 15);
    int rbase = f0 + fh * 16 + ((lane >> 4) << 2);
#pragma unroll
    for (int q = 0; q < 4; ++q) {
      size_t idx = (size_t)b * BS + (size_t)(rbase + q) * 256 + col;
      float sg = 1.f / (1.f + __expf(-acc[q]));
      out[idx] = sg + x[idx];
    }
  }
}

extern "C" void kernel_launch(void* const* d_in, const int* in_sizes, int n_in,
                              void* d_out, int out_size, void* d_ws,
                              size_t ws_size, hipStream_t stream) {
  const float* x = (const float*)d_in[0];
  const int* adj = (const int*)d_in[1];
  const float* W = (const float*)d_in[2];
  const float* b_lin = (const float*)d_in[3];
  const float* a = (const float*)d_in[4];
  const float* bias = (const float*)d_in[5];
  float* out = (float*)d_out;

  float* L2p = (float*)d_ws;                 // 8*65536 f32
  u32* R2p = (u32*)(L2p + BB * BS);          // 8*32768 u32 (packed bf16 pairs)
  u16* attnh = (u16*)(R2p + BB * 32768);     // 8*65536 u16
  int* cnt = (int*)(attnh + BB * BS);        // 8 counters

  d1_proj<<<512, 256, 0, stream>>>(x, W, b_lin, a, L2p, R2p, cnt);

  void* args[] = {&R2p, &L2p, &a, &adj, &bias, &x, &attnh, &out, &cnt};
  hipLaunchCooperativeKernel((const void*)d23_fused, dim3(512), dim3(256),
                             args, 0, stream);
}

// Round 11
// 28.920 us; speedup vs baseline: 4.1679x; 4.1679x over previous
//
#include <hip/hip_runtime.h>
#include <hip/hip_bf16.h>
#include <math.h>

#define BB 8
#define BS 65536  // 256*256

typedef __attribute__((ext_vector_type(8))) short short8v;
typedef __attribute__((ext_vector_type(4))) float f32x4;
typedef unsigned short u16;
typedef unsigned int u32;
typedef __attribute__((address_space(1))) const void gv_t;
typedef __attribute__((address_space(3))) void lv_t;

__device__ __forceinline__ u16 f2bf(float v) {
  __hip_bfloat16 h = __float2bfloat16(v);
  return *reinterpret_cast<u16*>(&h);
}

// MFMA LDS tiles: [32 rows][64 k] bf16 (4 KiB), row = 128 B = 8 chunks x 16 B.
// XOR swizzle cs = c ^ (r&7), applied identically on write and read (#21).
__device__ __forceinline__ short8v frag(const u16* lds, int rb, int sk,
                                        int lane) {
  int r = rb * 16 + (lane & 15);
  int c = sk * 4 + (lane >> 4);
  int cs = c ^ (r & 7);
  return *(const short8v*)(lds + r * 64 + cs * 8);
}

// gload_lds staging for a 32x64 bf16 tile: source pre-swizzled, LDS linear.
__device__ __forceinline__ void stage_g32(const u16* __restrict__ g, int row0,
                                          int stride, int k0, u16* lds,
                                          int tid) {
  int r = tid >> 3, c = tid & 7;
  int cs = c ^ (r & 7);
  const u16* src = g + (size_t)(row0 + r) * stride + k0 + cs * 8;
  u16* dst = lds + (size_t)(tid & ~63) * 8;  // wave-uniform base
  __builtin_amdgcn_global_load_lds((gv_t*)src, (lv_t*)dst, 16, 0, 0);
}

// ---------------------------------------------------------------------------
// D1: merged projection GEMMs, batch-affine (b = blockIdx & 7 -> XCD b).
//  L2p[b][n][dd] = |0.4a[dd]|*( sum_f x[f,n] W[dd,f] + b_lin[dd] )   (f32)
//  Rq[b][d4][n][2] = two packed-bf16-pair u32s covering d = 4*d4 .. +3
//      of R'(dd,n) = |0.4a[dd]| * sum_f x[f,n] W[dd,256+f]
// 512 blocks x 256 thr; block = (b, n0 = (t>>3)*32, dd0 = (t&7)*32).
// Software-pipelined (T14): ks+1 global loads issue before the MFMA phase of
// ks, hiding ~300cy load latency under sync + 8 MFMAs. 2 barriers per ks.
// ---------------------------------------------------------------------------
__global__ __launch_bounds__(256) void d1_proj(
    const float* __restrict__ x, const float* __restrict__ W,
    const float* __restrict__ b_lin, const float* __restrict__ a,
    float* __restrict__ L2p, u32* __restrict__ Rq) {
  __shared__ float xf[64][33];
  __shared__ u16 XT[32 * 64], B1[32 * 64], B2[32 * 64];
  const int bk = blockIdx.x, tid = threadIdx.x;
  const int b = bk & 7, t = bk >> 3;
  const int n0 = (t >> 3) * 32, dd0 = (t & 7) * 32;
  const int lane = tid & 63, wid = tid >> 6;
  const int nh = wid >> 1, dh = wid & 1;
  const float* xb = x + (size_t)b * BS;

  const int r8 = tid >> 5, c32 = tid & 31;   // x-tile staging coords
  const int rw = tid >> 3, cw = tid & 7;     // W / XT staging coords

  f32x4 accL = f32x4{0.f, 0.f, 0.f, 0.f};
  f32x4 accR = f32x4{0.f, 0.f, 0.f, 0.f};

  float xr[8];
  float4 wa0, wa1, wb0, wb1;

#define LOADX(KS)                                                          \
  {                                                                        \
    _Pragma("unroll") for (int it = 0; it < 8; ++it) xr[it] =              \
        xb[(size_t)((KS)*64 + it * 8 + r8) * 256 + n0 + c32];              \
  }
#define LOADW(KS)                                                          \
  {                                                                        \
    const float* wp = &W[(size_t)(dd0 + rw) * 512 + (KS)*64 + cw * 8];     \
    wa0 = *(const float4*)wp;                                              \
    wa1 = *(const float4*)(wp + 4);                                        \
    wb0 = *(const float4*)(wp + 256);                                      \
    wb1 = *(const float4*)(wp + 260);                                      \
  }
#define WRITE_XF()                                                         \
  {                                                                        \
    _Pragma("unroll") for (int it = 0; it < 8; ++it) xf[it * 8 + r8][c32] = \
        xr[it];                                                            \
  }

  LOADX(0);
  LOADW(0);
  WRITE_XF();

  for (int ks = 0; ks < 4; ++ks) {
    __syncthreads();  // xf(ks) ready; XT/B free from prev MFMA reads
    // P2: XT (transpose of xf, bf16, swizzled) + B1/B2 (W regs, bf16, swz)
    {
      u16 o[8];
#pragma unroll
      for (int e = 0; e < 8; ++e) o[e] = f2bf(xf[cw * 8 + e][rw]);
      *(short8v*)&XT[rw * 64 + ((cw ^ (rw & 7)) * 8)] = *(const short8v*)o;
      u16 o1[8] = {f2bf(wa0.x), f2bf(wa0.y), f2bf(wa0.z), f2bf(wa0.w),
                   f2bf(wa1.x), f2bf(wa1.y), f2bf(wa1.z), f2bf(wa1.w)};
      *(short8v*)&B1[rw * 64 + ((cw ^ (rw & 7)) * 8)] = *(const short8v*)o1;
      u16 o2[8] = {f2bf(wb0.x), f2bf(wb0.y), f2bf(wb0.z), f2bf(wb0.w),
                   f2bf(wb1.x), f2bf(wb1.y), f2bf(wb1.z), f2bf(wb1.w)};
      *(short8v*)&B2[rw * 64 + ((cw ^ (rw & 7)) * 8)] = *(const short8v*)o2;
    }
    // prefetch ks+1 (latency hides under sync + MFMA phase)
    if (ks < 3) {
      LOADX(ks + 1);
      LOADW(ks + 1);
    }
    __syncthreads();  // XT/B1/B2(ks) ready
    // P3: MFMA
#pragma unroll
    for (int sk = 0; sk < 2; ++sk) {
      short8v xa = frag(XT, nh, sk, lane);
      short8v w1 = frag(B1, dh, sk, lane);
      short8v w2 = frag(B2, dh, sk, lane);
      accL = __builtin_amdgcn_mfma_f32_16x16x32_bf16(xa, w1, accL, 0, 0, 0);
      accR = __builtin_amdgcn_mfma_f32_16x16x32_bf16(w2, xa, accR, 0, 0, 0);
    }
    if (ks < 3) WRITE_XF();  // xf(ks+1); P2(ks+1) reads after loop-top sync
  }
#undef LOADX
#undef LOADW
#undef WRITE_XF

  // epilogue: L2p[n][dd] (f32)
  {
    int ddc = dd0 + dh * 16 + (lane & 15);
    float c2 = fabsf(0.4f * a[ddc]);
    float bl = b_lin[ddc];
    int nr = n0 + nh * 16 + ((lane >> 4) << 2);
#pragma unroll
    for (int q = 0; q < 4; ++q)
      L2p[(size_t)b * BS + (size_t)(nr + q) * 256 + ddc] = c2 * (accL[q] + bl);
  }
  // epilogue: Rq[d4][n][2] packed bf16 pairs, one uint2 store per thread
  {
    int nc = n0 + nh * 16 + (lane & 15);
    int ddr = dd0 + dh * 16 + ((lane >> 4) << 2);  // multiple of 4
    float r0 = fabsf(0.4f * a[ddr + 0]) * accR[0];
    float r1 = fabsf(0.4f * a[ddr + 1]) * accR[1];
    float r2 = fabsf(0.4f * a[ddr + 2]) * accR[2];
    float r3 = fabsf(0.4f * a[ddr + 3]) * accR[3];
    uint2 p;
    p.x = (u32)f2bf(r0) | ((u32)f2bf(r1) << 16);
    p.y = (u32)f2bf(r2) | ((u32)f2bf(r3) << 16);
    *(uint2*)&Rq[(size_t)b * 32768 + (size_t)(ddr >> 2) * 512 + nc * 2] = p;
  }
}

// ---------------------------------------------------------------------------
// D2: e[i,j] = 1.5*sum_d sgn*R + bias + sum_d sgn[d]*|L2p[i,d]+R[d,j]|,
// mask, softmax over j -> attnh bf16 [i][j].
// 512 blocks x 256 thr (2 blocks/CU), batch-affine: b = bk&7, i0=(bk>>3)*4.
// Barrier-free inner loop: 64 uint2 loads/thread (4 d-values each, coalesced
// 512B/wave), unroll 8 for ILP. adj/bias issued early.
// ---------------------------------------------------------------------------
__global__ __launch_bounds__(256, 2) void d2_scores(
    const u32* __restrict__ Rq, const float* __restrict__ L2p,
    const float* __restrict__ a, const int* __restrict__ adj,
    const float* __restrict__ bias, u16* __restrict__ attnh) {
  __shared__ float4 Lq[256];   // 4 rows i0..i0+3 at col d
  __shared__ float2 sS2[128];  // sign pairs
  __shared__ float redm[4][4], reds[4][4];
  const int tid = threadIdx.x, j = tid;
  const int bk = blockIdx.x, b = bk & 7, i0 = (bk >> 3) * 4;
  const int lane = tid & 63, wid = tid >> 6;
  const u32* Rb = Rq + (size_t)b * 32768;

  // early mask/bias loads (consumed after the d-loop)
  int adjv[4];
  float biasv[4];
#pragma unroll
  for (int ii = 0; ii < 4; ++ii) {
    int row = i0 + ii;
    adjv[ii] = adj[(size_t)b * BS + (size_t)row * 256 + j];
    biasv[ii] = bias[row * 256 + j];
  }
  {
    const float* Lb = L2p + (size_t)b * BS + (size_t)i0 * 256;
    Lq[j] = make_float4(Lb[j], Lb[256 + j], Lb[512 + j], Lb[768 + j]);
    if (tid < 128) {
      float2 av = *(const float2*)&a[2 * tid];
      sS2[tid] = make_float2(av.x >= 0.f ? 1.f : -1.f, av.y >= 0.f ? 1.f : -1.f);
    }
  }
  __syncthreads();

  float e0 = 0.f, e1 = 0.f, e2 = 0.f, e3 = 0.f, srj = 0.f;
#pragma unroll 8
  for (int d4 = 0; d4 < 64; ++d4) {
    uint2 u = *(const uint2*)&Rb[(size_t)d4 * 512 + 2 * j];  // 4 d-values
    float rv0 = __uint_as_float(u.x << 16);
    float rv1 = __uint_as_float(u.x & 0xffff0000u);
    float rv2 = __uint_as_float(u.y << 16);
    float rv3 = __uint_as_float(u.y & 0xffff0000u);
    float2 sa = sS2[2 * d4], sb = sS2[2 * d4 + 1];
    float4 lq0 = Lq[4 * d4], lq1 = Lq[4 * d4 + 1];
    float4 lq2 = Lq[4 * d4 + 2], lq3 = Lq[4 * d4 + 3];
    srj = fmaf(sa.x, rv0, srj);
    srj = fmaf(sa.y, rv1, srj);
    srj = fmaf(sb.x, rv2, srj);
    srj = fmaf(sb.y, rv3, srj);
    e0 = fmaf(sa.x, fabsf(lq0.x + rv0), e0);
    e1 = fmaf(sa.x, fabsf(lq0.y + rv0), e1);
    e2 = fmaf(sa.x, fabsf(lq0.z + rv0), e2);
    e3 = fmaf(sa.x, fabsf(lq0.w + rv0), e3);
    e0 = fmaf(sa.y, fabsf(lq1.x + rv1), e0);
    e1 = fmaf(sa.y, fabsf(lq1.y + rv1), e1);
    e2 = fmaf(sa.y, fabsf(lq1.z + rv1), e2);
    e3 = fmaf(sa.y, fabsf(lq1.w + rv1), e3);
    e0 = fmaf(sb.x, fabsf(lq2.x + rv2), e0);
    e1 = fmaf(sb.x, fabsf(lq2.y + rv2), e1);
    e2 = fmaf(sb.x, fabsf(lq2.z + rv2), e2);
    e3 = fmaf(sb.x, fabsf(lq2.w + rv2), e3);
    e0 = fmaf(sb.y, fabsf(lq3.x + rv3), e0);
    e1 = fmaf(sb.y, fabsf(lq3.y + rv3), e1);
    e2 = fmaf(sb.y, fabsf(lq3.z + rv3), e2);
    e3 = fmaf(sb.y, fabsf(lq3.w + rv3), e3);
  }

  float ev[4] = {e0, e1, e2, e3};
  const float sbase = 1.5f * srj;
  const float NEG_INF = -__builtin_inff();
#pragma unroll
  for (int ii = 0; ii < 4; ++ii) {
    ev[ii] += sbase + biasv[ii];
    ev[ii] = (adjv[ii] == 0) ? NEG_INF : ev[ii];
  }
#pragma unroll
  for (int ii = 0; ii < 4; ++ii) {
    float v = ev[ii];
#pragma unroll
    for (int off = 32; off >= 1; off >>= 1) v = fmaxf(v, __shfl_xor(v, off, 64));
    if (lane == 0) redm[wid][ii] = v;
  }
  __syncthreads();
  float p4[4];
#pragma unroll
  for (int ii = 0; ii < 4; ++ii) {
    float m = fmaxf(fmaxf(redm[0][ii], redm[1][ii]),
                    fmaxf(redm[2][ii], redm[3][ii]));
    p4[ii] = (m == NEG_INF) ? 1.f : __expf(ev[ii] - m);
  }
#pragma unroll
  for (int ii = 0; ii < 4; ++ii) {
    float v = p4[ii];
#pragma unroll
    for (int off = 32; off >= 1; off >>= 1) v += __shfl_xor(v, off, 64);
    if (lane == 0) reds[wid][ii] = v;
  }
  __syncthreads();
#pragma unroll
  for (int ii = 0; ii < 4; ++ii) {
    float ssum = reds[0][ii] + reds[1][ii] + reds[2][ii] + reds[3][ii];
    attnh[(size_t)b * BS + (size_t)(i0 + ii) * 256 + j] = f2bf(p4[ii] / ssum);
  }
}

// ---------------------------------------------------------------------------
// D3: out[b][f][i] = sigmoid( sum_j x[f][j]*attn[i][j] ) + x[b][f][i]
// batch-affine, 512 blocks x 256 thr; block = (b, f0, i0). A = x rows f
// (reg-staged f32->bf16, swizzled ds_write); B = attnh rows i (gload_lds).
// ---------------------------------------------------------------------------
__global__ __launch_bounds__(256) void d3_out(const u16* __restrict__ attnh,
                                              const float* __restrict__ x,
                                              float* __restrict__ out) {
  __shared__ u16 At[32 * 64], Bt[32 * 64];
  const int bk = blockIdx.x, tid = threadIdx.x;
  const int b = bk & 7, t = bk >> 3;
  const int f0 = (t >> 3) * 32, i0 = (t & 7) * 32;
  const int lane = tid & 63, wid = tid >> 6;
  const int fh = wid >> 1, ih2 = wid & 1;
  const float* Ax = x + (size_t)b * BS;
  const u16* Bb = attnh + (size_t)b * BS;
  const int rw = tid >> 3, cw = tid & 7;

  f32x4 acc = f32x4{0.f, 0.f, 0.f, 0.f};
  for (int ks = 0; ks < 4; ++ks) {
    stage_g32(Bb, i0, 256, ks * 64, Bt, tid);
    {
      const float* src = Ax + (size_t)(f0 + rw) * 256 + ks * 64 + cw * 8;
      float4 v0 = *(const float4*)src;
      float4 v1 = *(const float4*)(src + 4);
      u16 o[8] = {f2bf(v0.x), f2bf(v0.y), f2bf(v0.z), f2bf(v0.w),
                  f2bf(v1.x), f2bf(v1.y), f2bf(v1.z), f2bf(v1.w)};
      *(short8v*)&At[rw * 64 + ((cw ^ (rw & 7)) * 8)] = *(const short8v*)o;
    }
    __syncthreads();
#pragma unroll
    for (int sk = 0; sk < 2; ++sk) {
      short8v af = frag(At, fh, sk, lane);
      short8v bf = frag(Bt, ih2, sk, lane);
      acc = __builtin_amdgcn_mfma_f32_16x16x32_bf16(af, bf, acc, 0, 0, 0);
    }
    __syncthreads();
  }

  int col = i0 + ih2 * 16 + (lane & 15);
  int rbase = f0 + fh * 16 + ((lane >> 4) << 2);
#pragma unroll
  for (int q = 0; q < 4; ++q) {
    size_t idx = (size_t)b * BS + (size_t)(rbase + q) * 256 + col;
    float sg = 1.f / (1.f + __expf(-acc[q]));
    out[idx] = sg + x[idx];
  }
}

extern "C" void kernel_launch(void* const* d_in, const int* in_sizes, int n_in,
                              void* d_out, int out_size, void* d_ws,
                              size_t ws_size, hipStream_t stream) {
  const float* x = (const float*)d_in[0];
  const int* adj = (const int*)d_in[1];
  const float* W = (const float*)d_in[2];
  const float* b_lin = (const float*)d_in[3];
  const float* a = (const float*)d_in[4];
  const float* bias = (const float*)d_in[5];
  float* out = (float*)d_out;

  float* L2p = (float*)d_ws;                 // 8*65536 f32
  u32* Rq = (u32*)(L2p + BB * BS);           // 8*32768 u32 (packed, [d4][n][2])
  u16* attnh = (u16*)(Rq + BB * 32768);      // 8*65536 u16

  d1_proj<<<512, 256, 0, stream>>>(x, W, b_lin, a, L2p, Rq);
  d2_scores<<<512, 256, 0, stream>>>(Rq, L2p, a, adj, bias, attnh);
  d3_out<<<512, 256, 0, stream>>>(attnh, x, out);
}